// Round 6
// baseline (213.993 us; speedup 1.0000x reference)
//
#include <hip/hip_runtime.h>
#include <hip/hip_cooperative_groups.h>

namespace cg = cooperative_groups;

// x, enhance_x : (16, 3, 512, 512) fp32.
// Phase 1: q[b,i,j] = mean_{c,4x4}(x) - mean_{c,4x4}(e)   (16x128x128, 1 MB in ws)
// grid.sync()
// Phase 2: out = sum over 4 dirs of (q_c - q_nb)^2, zero-padded neighbors.
// Cooperative single launch: 1024 blocks x 256 threads (4 blocks/CU, co-resident).

__global__ __launch_bounds__(256) void spatial_loss_coop(
    const float* __restrict__ x, const float* __restrict__ e,
    float* __restrict__ out, float* __restrict__ q)
{
    cg::grid_group grid = cg::this_grid();

    int tid = blockIdx.x * 256 + threadIdx.x;     // exactly 262144 threads
    int b   = tid >> 14;                          // batch
    int rem = tid & 16383;
    int i   = rem >> 7;                           // pooled row 0..127
    int j   = rem & 127;                          // pooled col (= float4 column)

    // ---- Phase 1: pooled-gray difference ----
    const float4* xb = reinterpret_cast<const float4*>(x) + (size_t)b * 3 * 512 * 128;
    const float4* eb = reinterpret_cast<const float4*>(e) + (size_t)b * 3 * 512 * 128;

    int row0 = i << 2;
    float sx = 0.0f, se = 0.0f;
#pragma unroll
    for (int c = 0; c < 3; ++c) {
#pragma unroll
        for (int di = 0; di < 4; ++di) {
            int off = (c * 512 + row0 + di) * 128 + j;
            float4 vx = xb[off];
            float4 ve = eb[off];
            sx += (vx.x + vx.y) + (vx.z + vx.w);
            se += (ve.x + ve.y) + (ve.z + ve.w);
        }
    }
    q[tid] = (sx - se) * (1.0f / 48.0f);

    // ---- grid-wide barrier (device-scope visibility) ----
    grid.sync();

    // ---- Phase 2: 4-direction squared differences ----
    const float* qb = q + (tid & ~16383);         // batch base
    float qc = qb[rem];
    float ql = (j > 0)   ? qb[rem - 1]   : 0.0f;
    float qr = (j < 127) ? qb[rem + 1]   : 0.0f;
    float qu = (i > 0)   ? qb[rem - 128] : 0.0f;
    float qd = (i < 127) ? qb[rem + 128] : 0.0f;

    float dl = qc - ql, dr = qc - qr, du = qc - qu, dd = qc - qd;
    out[tid] = dl * dl + dr * dr + du * du + dd * dd;
}

extern "C" void kernel_launch(void* const* d_in, const int* in_sizes, int n_in,
                              void* d_out, int out_size, void* d_ws, size_t ws_size,
                              hipStream_t stream) {
    const float* x = (const float*)d_in[0];
    const float* e = (const float*)d_in[1];
    float* out = (float*)d_out;
    float* q   = (float*)d_ws;                    // 1 MiB scratch

    void* args[] = { (void*)&x, (void*)&e, (void*)&out, (void*)&q };
    hipLaunchCooperativeKernel((void*)spatial_loss_coop,
                               dim3(1024), dim3(256), args, 0, stream);
}

// Round 8
// 113.728 us; speedup vs baseline: 1.8816x; 1.8816x over previous
//
#include <hip/hip_runtime.h>

// Problem: x, enhance_x : (16, 3, 512, 512) fp32
// q[b,i,j] = mean_{c,4x4}(x) - mean_{c,4x4}(enhance_x)   (128x128 per batch)
// out[b,i,j] = sum over 4 neighbor dirs of (q_center - q_neighbor)^2, zero-padded.
//
// Two-kernel structure (best measured: round-1, 114.8 us total window).
// Kernel 1 reads the compulsory 100.7 MB (fully coalesced float4), writes 1 MB q.
// Kernel 2 reads L2-resident q + writes 1 MB out. Fusion attempts (halo
// recompute +2.7us, cooperative grid.sync +99us) both measured worse.

#define B_  16
#define QHW (128 * 128)          // 16384 q pixels per batch
#define NQ  (B_ * QHW)           // 262144 total

__global__ __launch_bounds__(256) void pool_diff_kernel(
    const float* __restrict__ x, const float* __restrict__ e,
    float* __restrict__ q)
{
    int tid = blockIdx.x * 256 + threadIdx.x;     // exactly NQ threads
    int b   = tid >> 14;                          // / 16384
    int rem = tid & 16383;
    int i   = rem >> 7;                           // pooled row 0..127
    int j   = rem & 127;                          // pooled col 0..127 (= float4 column)

    // Batch base in units of float4: b * 3ch * 512rows * 128 float4/row
    const float4* xb = reinterpret_cast<const float4*>(x) + (size_t)b * 3 * 512 * 128;
    const float4* eb = reinterpret_cast<const float4*>(e) + (size_t)b * 3 * 512 * 128;

    int row0 = i << 2;
    float sx = 0.0f, se = 0.0f;
#pragma unroll
    for (int c = 0; c < 3; ++c) {
#pragma unroll
        for (int di = 0; di < 4; ++di) {
            int off = (c * 512 + row0 + di) * 128 + j;
            float4 vx = xb[off];
            float4 ve = eb[off];
            sx += (vx.x + vx.y) + (vx.z + vx.w);
            se += (ve.x + ve.y) + (ve.z + ve.w);
        }
    }
    q[tid] = (sx - se) * (1.0f / 48.0f);
}

__global__ __launch_bounds__(256) void dir_loss_kernel(
    const float* __restrict__ q, float* __restrict__ out)
{
    int tid = blockIdx.x * 256 + threadIdx.x;     // exactly NQ threads
    int rem = tid & 16383;
    int i   = rem >> 7;
    int j   = rem & 127;

    const float* qb = q + (tid & ~16383);         // batch base
    float qc = qb[rem];
    float ql = (j > 0)   ? qb[rem - 1]   : 0.0f;
    float qr = (j < 127) ? qb[rem + 1]   : 0.0f;
    float qu = (i > 0)   ? qb[rem - 128] : 0.0f;
    float qd = (i < 127) ? qb[rem + 128] : 0.0f;

    float dl = qc - ql, dr = qc - qr, du = qc - qu, dd = qc - qd;
    out[tid] = dl * dl + dr * dr + du * du + dd * dd;
}

extern "C" void kernel_launch(void* const* d_in, const int* in_sizes, int n_in,
                              void* d_out, int out_size, void* d_ws, size_t ws_size,
                              hipStream_t stream) {
    const float* x = (const float*)d_in[0];
    const float* e = (const float*)d_in[1];
    float* out = (float*)d_out;
    float* q   = (float*)d_ws;                    // NQ floats = 1 MiB scratch

    dim3 grid(NQ / 256), block(256);
    pool_diff_kernel<<<grid, block, 0, stream>>>(x, e, q);
    dir_loss_kernel<<<grid, block, 0, stream>>>(q, out);
}